// Round 6
// baseline (226.380 us; speedup 1.0000x reference)
//
#include <hip/hip_runtime.h>
#include <math.h>
#include <utility>

static constexpr int HH = 2048;
static constexpr int WW = 2048;
static constexpr int NPIX = HH * WW;
static constexpr int WPR = WW / 64;        // 32 packed u64 words per row
static constexpr int NBLK = 1024;          // 4 blocks/CU x 256 CUs -> all resident
static constexpr int NTHR = NBLK * 256;

// Compile-time-forced loop unrolling (keeps acc[] in registers).
template <typename F, int... Is>
__device__ __forceinline__ void sf_impl(F&& f, std::integer_sequence<int, Is...>) {
    (f(std::integral_constant<int, Is>{}), ...);
}
template <int N, typename F>
__device__ __forceinline__ void static_for(F&& f) {
    sf_impl(f, std::make_integer_sequence<int, N>{});
}

// Rank of squared distance among the 14 distinct d2 values in the 9x9
// neighborhood (ascending). 0 = "no differing neighbor".
__host__ __device__ constexpr int rank_of(int d2) {
    switch (d2) {
        case 1:  return 1;  case 2:  return 2;  case 4:  return 3;
        case 5:  return 4;  case 8:  return 5;  case 9:  return 6;
        case 10: return 7;  case 13: return 8;  case 16: return 9;
        case 17: return 10; case 18: return 11; case 20: return 12;
        case 25: return 13; case 32: return 14;
    }
    return 0;
}

__device__ const int D2S[16] = {0, 1, 2, 4, 5, 8, 9, 10, 13, 16, 17, 18, 20, 25, 32, 0};

// Spread the 8 bits of b into the 8 bytes of a u64 (byte i = (b>>i)&1).
__device__ __forceinline__ unsigned long long spread8(unsigned int b) {
    unsigned long long t = (unsigned long long)b * 0x0101010101010101ull;
    t &= 0x8040201008040201ull;
    return ((t + 0x7f7f7f7f7f7f7f7full) >> 7) & 0x0101010101010101ull;
}

// Monotonic-ticket grid barrier (ockl grid_sync pattern: one representative
// thread, agent-scope acq_rel arrival + acquire spin). cnt must start at a
// multiple of NBLK each launch (memset to 0 in kernel_launch).
__device__ __forceinline__ void grid_barrier(unsigned* cnt) {
    __syncthreads();
    if (threadIdx.x == 0) {
        unsigned t = __hip_atomic_fetch_add(cnt, 1u, __ATOMIC_ACQ_REL,
                                            __HIP_MEMORY_SCOPE_AGENT);
        unsigned target = (t / NBLK + 1u) * NBLK;
        while (__hip_atomic_load(cnt, __ATOMIC_ACQUIRE,
                                 __HIP_MEMORY_SCOPE_AGENT) < target)
            __builtin_amdgcn_s_sleep(2);
    }
    __syncthreads();
}

__global__ __launch_bounds__(256, 4) void k_fused(
        const float* __restrict__ t,
        unsigned long long* __restrict__ fw8,     // NPIX bytes as u64[NPIX/8]
        unsigned char* __restrict__ pkb,          // NPIX/8 bytes (bit-packed)
        unsigned* __restrict__ cnt,               // barrier ticket
        unsigned long long* __restrict__ obs,     // observed-code mask [2]
        float* __restrict__ out) {
    const int gid = blockIdx.x * 256 + threadIdx.x;

    // LDS: this block's 4096 pixel codes (phase2 -> phase3), + table state.
    __shared__ unsigned long long sc8[512];       // 4 KB
    __shared__ float tab[96];
    __shared__ float smn[4], smx[4];
    __shared__ unsigned long long sobs[2];

    // ---- Phase 1: fw byte map + bit-packed combined mask (8 px/thread/iter) ----
#pragma unroll
    for (int it = 0; it < 2; ++it) {
        const int i = gid + it * NTHR;
        const int base = i * 8;
        unsigned long long fwq = 0;
        unsigned int bits = 0;
#pragma unroll
        for (int h = 0; h < 2; ++h) {
            const int o = base + 4 * h;
            float4 a = *(const float4*)(t + 0 * NPIX + o);
            float4 b = *(const float4*)(t + 1 * NPIX + o);
            float4 c = *(const float4*)(t + 2 * NPIX + o);
            float4 d = *(const float4*)(t + 3 * NPIX + o);
            float4 e = *(const float4*)(t + 4 * NPIX + o);
            const float s0 = a.x + b.x + c.x + d.x + e.x;
            const float s1 = a.y + b.y + c.y + d.y + e.y;
            const float s2 = a.z + b.z + c.z + d.z + e.z;
            const float s3 = a.w + b.w + c.w + d.w + e.w;
            const int j = 4 * h;
            fwq |= ((unsigned long long)(int)s0) << (8 * j);
            fwq |= ((unsigned long long)(int)s1) << (8 * (j + 1));
            fwq |= ((unsigned long long)(int)s2) << (8 * (j + 2));
            fwq |= ((unsigned long long)(int)s3) << (8 * (j + 3));
            bits |= (s0 > 0.f ? 1u : 0u) << j;
            bits |= (s1 > 0.f ? 1u : 0u) << (j + 1);
            bits |= (s2 > 0.f ? 1u : 0u) << (j + 2);
            bits |= (s3 > 0.f ? 1u : 0u) << (j + 3);
        }
        fw8[i] = fwq;
        pkb[i] = (unsigned char)bits;
    }

    grid_barrier(cnt);

    // ---- Phase 2: bit-parallel distance classes; wave 0 handles this
    // block's 64 words (= its 4096 output pixels), codes stay in LDS ----
    if (threadIdx.x < 64) {
        const unsigned long long* pk = (const unsigned long long*)pkb;
        const int w = blockIdx.x * 64 + threadIdx.x;
        const int y = w >> 5;
        const int wx = w & (WPR - 1);

        unsigned long long acc[15];
        static_for<15>([&](auto I) { acc[I.value] = 0ull; });

        const unsigned long long C = pk[y * WPR + wx];

        static_for<9>([&](auto DY) {
            constexpr int dy = DY.value - 4;
            const int yy = min(max(y + dy, 0), HH - 1);
            const unsigned long long M = pk[yy * WPR + wx];
            const unsigned long long L =
                (wx > 0) ? pk[yy * WPR + wx - 1] : ((M & 1ull) ? ~0ull : 0ull);
            const unsigned long long R =
                (wx < WPR - 1) ? pk[yy * WPR + wx + 1] : ((M >> 63) ? ~0ull : 0ull);
            static_for<9>([&](auto DX) {
                constexpr int dx = DX.value - 4;
                if constexpr (!(dx == 0 && dy == 0)) {
                    constexpr int rk = rank_of(dy * dy + dx * dx);
                    unsigned long long S;
                    if constexpr (dx > 0)      S = (M >> dx) | (R << (64 - dx));
                    else if constexpr (dx < 0) S = (M << (-dx)) | (L >> (64 + dx));
                    else                       S = M;
                    acc[rk] |= S ^ C;
                }
            });
        });

        unsigned long long found = 0, p0 = 0, p1 = 0, p2 = 0, p3 = 0;
        static_for<14>([&](auto RI) {
            constexpr int r = RI.value + 1;
            const unsigned long long nw = acc[r] & ~found;
            found |= acc[r];
            if constexpr (r & 1) p0 |= nw;
            if constexpr (r & 2) p1 |= nw;
            if constexpr (r & 4) p2 |= nw;
            if constexpr (r & 8) p3 |= nw;
        });

        unsigned long long lo = 0, hi = 0;
        static_for<8>([&](auto J) {
            constexpr int j = J.value;
            const unsigned long long f = fw8[w * 8 + j];
            const unsigned int c0 = (unsigned int)((p0 >> (8 * j)) & 0xff);
            const unsigned int c1 = (unsigned int)((p1 >> (8 * j)) & 0xff);
            const unsigned int c2 = (unsigned int)((p2 >> (8 * j)) & 0xff);
            const unsigned int c3 = (unsigned int)((p3 >> (8 * j)) & 0xff);
            const unsigned long long cls = spread8(c0) | (spread8(c1) << 1)
                                         | (spread8(c2) << 2) | (spread8(c3) << 3);
            const unsigned long long cq = (f << 4) | cls;  // fv<=5, no overflow
            sc8[threadIdx.x * 8 + j] = cq;
            static_for<8>([&](auto B) {
                constexpr int b = B.value;
                const unsigned int code = (unsigned int)((cq >> (8 * b)) & 0xff);
                const unsigned long long bit = 1ull << (code & 63);
                const bool ishi = (code & 64) != 0;
                lo |= ishi ? 0ull : bit;
                hi |= ishi ? bit : 0ull;
            });
        });

#pragma unroll
        for (int s = 32; s > 0; s >>= 1) {
            lo |= __shfl_xor(lo, s);
            hi |= __shfl_xor(hi, s);
        }
        if (threadIdx.x == 0) {
            atomicOr(&obs[0], lo);   // device-scope, before barrier release
            atomicOr(&obs[1], hi);
        }
    }

    grid_barrier(cnt);

    // ---- Phase 3: per-block 96-entry table + LDS-code lookup, coalesced out ----
    const int tid = threadIdx.x;
    if (tid < 2)
        sobs[tid] = __hip_atomic_load(&obs[tid], __ATOMIC_RELAXED,
                                      __HIP_MEMORY_SCOPE_AGENT);
    __syncthreads();
    const unsigned long long lo = sobs[0], hi = sobs[1];

    float v = 0.f;
    bool present = false;
    if (tid < 96) {
        const int r = tid & 15;
        const float contour = (r >= 1 && r <= 14) ? 1.f / sqrtf((float)D2S[r]) : 0.f;
        const float t0 = (float)(tid >> 4) + contour;
        v = t0 * t0;
        present = (tid < 64) ? ((lo >> tid) & 1) : ((hi >> (tid - 64)) & 1);
    }
    float mnv = present ? v : INFINITY;
    float mxv = present ? v : -INFINITY;
#pragma unroll
    for (int s = 32; s > 0; s >>= 1) {
        mnv = fminf(mnv, __shfl_xor(mnv, s));
        mxv = fmaxf(mxv, __shfl_xor(mxv, s));
    }
    if ((tid & 63) == 0) { smn[tid >> 6] = mnv; smx[tid >> 6] = mxv; }
    __syncthreads();
    const float mn = fminf(fminf(smn[0], smn[1]), fminf(smn[2], smn[3]));
    const float mx = fmaxf(fmaxf(smx[0], smx[1]), fmaxf(smx[2], smx[3]));
    const float inv = 1.f / (mx - mn + 1e-10f);
    if (tid < 96) tab[tid] = (tid >= 16) ? (v - mn) * inv : 0.f;  // fv==0 -> 0
    __syncthreads();

    const unsigned int* sc32 = (const unsigned int*)sc8;
#pragma unroll
    for (int k = 0; k < 4; ++k) {
        const unsigned int cw = sc32[k * 256 + tid];   // 4 px codes
        float4 o;
        o.x = tab[cw & 0xff];
        o.y = tab[(cw >> 8) & 0xff];
        o.z = tab[(cw >> 16) & 0xff];
        o.w = tab[(cw >> 24) & 0xff];
        *(float4*)(out + blockIdx.x * 4096 + k * 1024 + tid * 4) = o;
    }
}

extern "C" void kernel_launch(void* const* d_in, const int* in_sizes, int n_in,
                              void* d_out, int out_size, void* d_ws, size_t ws_size,
                              hipStream_t stream) {
    const float* target = (const float*)d_in[0];
    float* out = (float*)d_out;

    // ws layout: fw (NPIX B) | pk (NPIX/8 B) | {cnt u32, pad u32, obs u64[2]}
    unsigned long long* fw8 = (unsigned long long*)d_ws;
    unsigned char* pkb = (unsigned char*)d_ws + NPIX;
    unsigned char* barp = pkb + NPIX / 8;
    unsigned* cnt = (unsigned*)barp;
    unsigned long long* obs = (unsigned long long*)(barp + 8);

    // Reset barrier ticket + observed-code mask (graph-capturable memset).
    hipMemsetAsync(barp, 0, 24, stream);

    k_fused<<<NBLK, 256, 0, stream>>>(target, fw8, pkb, cnt, obs, out);
}

// Round 7
// 216.674 us; speedup vs baseline: 1.0448x; 1.0448x over previous
//
#include <hip/hip_runtime.h>
#include <math.h>
#include <utility>

static constexpr int HH = 2048;
static constexpr int WW = 2048;
static constexpr int NPIX = HH * WW;
static constexpr int WPR = WW / 64;        // 32 packed u64 words per row
static constexpr int NBLK = 1024;          // 4 blocks/CU x 256 CUs -> all resident
static constexpr int NTHR = NBLK * 256;

// Compile-time-forced loop unrolling (keeps acc[] in registers).
template <typename F, int... Is>
__device__ __forceinline__ void sf_impl(F&& f, std::integer_sequence<int, Is...>) {
    (f(std::integral_constant<int, Is>{}), ...);
}
template <int N, typename F>
__device__ __forceinline__ void static_for(F&& f) {
    sf_impl(f, std::make_integer_sequence<int, N>{});
}

// Rank of squared distance among the 14 distinct d2 values in the 9x9
// neighborhood (ascending). 0 = "no differing neighbor".
__host__ __device__ constexpr int rank_of(int d2) {
    switch (d2) {
        case 1:  return 1;  case 2:  return 2;  case 4:  return 3;
        case 5:  return 4;  case 8:  return 5;  case 9:  return 6;
        case 10: return 7;  case 13: return 8;  case 16: return 9;
        case 17: return 10; case 18: return 11; case 20: return 12;
        case 25: return 13; case 32: return 14;
    }
    return 0;
}

__device__ const int D2S[16] = {0, 1, 2, 4, 5, 8, 9, 10, 13, 16, 17, 18, 20, 25, 32, 0};

// Spread the 8 bits of b into the 8 bytes of a u64 (byte i = (b>>i)&1).
__device__ __forceinline__ unsigned long long spread8(unsigned int b) {
    unsigned long long t = (unsigned long long)b * 0x0101010101010101ull;
    t &= 0x8040201008040201ull;
    return ((t + 0x7f7f7f7f7f7f7f7full) >> 7) & 0x0101010101010101ull;
}

// Monotonic-ticket grid barrier. KEY (R6 lesson): poll with RELAXED loads —
// an ACQUIRE poll invalidates the XCD's L2 every iteration (per-XCD L2s are
// non-coherent, so agent-acquire => L2 inv) and that thrashed the whole chip
// (247us, VALUBusy 2%). One RELEASE at arrival + one ACQUIRE fence at exit.
__device__ __forceinline__ void grid_barrier(unsigned* cnt) {
    __syncthreads();
    if (threadIdx.x == 0) {
        const unsigned t = __hip_atomic_fetch_add(cnt, 1u, __ATOMIC_RELEASE,
                                                  __HIP_MEMORY_SCOPE_AGENT);
        const unsigned target = (t / NBLK + 1u) * NBLK;
        while (__hip_atomic_load(cnt, __ATOMIC_RELAXED,
                                 __HIP_MEMORY_SCOPE_AGENT) < target)
            __builtin_amdgcn_s_sleep(8);
        __builtin_amdgcn_fence(__ATOMIC_ACQUIRE, "agent");
    }
    __syncthreads();
}

__global__ __launch_bounds__(256, 4) void k_fused(
        const float* __restrict__ t,
        unsigned long long* __restrict__ fw8,     // NPIX bytes as u64[NPIX/8]
        unsigned char* __restrict__ pkb,          // NPIX/8 bytes (bit-packed)
        unsigned* __restrict__ cnt,               // barrier ticket
        unsigned long long* __restrict__ obs,     // observed-code mask [2]
        float* __restrict__ out) {
    const int gid = blockIdx.x * 256 + threadIdx.x;

    // LDS: this block's 4096 pixel codes (phase2 -> phase3), + table state.
    __shared__ unsigned long long sc8[512];       // 4 KB
    __shared__ float tab[96];
    __shared__ float smn[4], smx[4];
    __shared__ unsigned long long sobs[2];

    // ---- Phase 1: fw byte map + bit-packed combined mask (8 px/thread/iter) ----
#pragma unroll
    for (int it = 0; it < 2; ++it) {
        const int i = gid + it * NTHR;
        const int base = i * 8;
        unsigned long long fwq = 0;
        unsigned int bits = 0;
#pragma unroll
        for (int h = 0; h < 2; ++h) {
            const int o = base + 4 * h;
            float4 a = *(const float4*)(t + 0 * NPIX + o);
            float4 b = *(const float4*)(t + 1 * NPIX + o);
            float4 c = *(const float4*)(t + 2 * NPIX + o);
            float4 d = *(const float4*)(t + 3 * NPIX + o);
            float4 e = *(const float4*)(t + 4 * NPIX + o);
            const float s0 = a.x + b.x + c.x + d.x + e.x;
            const float s1 = a.y + b.y + c.y + d.y + e.y;
            const float s2 = a.z + b.z + c.z + d.z + e.z;
            const float s3 = a.w + b.w + c.w + d.w + e.w;
            const int j = 4 * h;
            fwq |= ((unsigned long long)(int)s0) << (8 * j);
            fwq |= ((unsigned long long)(int)s1) << (8 * (j + 1));
            fwq |= ((unsigned long long)(int)s2) << (8 * (j + 2));
            fwq |= ((unsigned long long)(int)s3) << (8 * (j + 3));
            bits |= (s0 > 0.f ? 1u : 0u) << j;
            bits |= (s1 > 0.f ? 1u : 0u) << (j + 1);
            bits |= (s2 > 0.f ? 1u : 0u) << (j + 2);
            bits |= (s3 > 0.f ? 1u : 0u) << (j + 3);
        }
        fw8[i] = fwq;
        pkb[i] = (unsigned char)bits;
    }

    grid_barrier(cnt);

    // ---- Phase 2: bit-parallel distance classes; wave 0 handles this
    // block's 64 words (= its 4096 output pixels), codes stay in LDS ----
    if (threadIdx.x < 64) {
        const unsigned long long* pk = (const unsigned long long*)pkb;
        const int w = blockIdx.x * 64 + threadIdx.x;
        const int y = w >> 5;
        const int wx = w & (WPR - 1);

        unsigned long long acc[15];
        static_for<15>([&](auto I) { acc[I.value] = 0ull; });

        const unsigned long long C = pk[y * WPR + wx];

        static_for<9>([&](auto DY) {
            constexpr int dy = DY.value - 4;
            const int yy = min(max(y + dy, 0), HH - 1);
            const unsigned long long M = pk[yy * WPR + wx];
            const unsigned long long L =
                (wx > 0) ? pk[yy * WPR + wx - 1] : ((M & 1ull) ? ~0ull : 0ull);
            const unsigned long long R =
                (wx < WPR - 1) ? pk[yy * WPR + wx + 1] : ((M >> 63) ? ~0ull : 0ull);
            static_for<9>([&](auto DX) {
                constexpr int dx = DX.value - 4;
                if constexpr (!(dx == 0 && dy == 0)) {
                    constexpr int rk = rank_of(dy * dy + dx * dx);
                    unsigned long long S;
                    if constexpr (dx > 0)      S = (M >> dx) | (R << (64 - dx));
                    else if constexpr (dx < 0) S = (M << (-dx)) | (L >> (64 + dx));
                    else                       S = M;
                    acc[rk] |= S ^ C;
                }
            });
        });

        unsigned long long found = 0, p0 = 0, p1 = 0, p2 = 0, p3 = 0;
        static_for<14>([&](auto RI) {
            constexpr int r = RI.value + 1;
            const unsigned long long nw = acc[r] & ~found;
            found |= acc[r];
            if constexpr (r & 1) p0 |= nw;
            if constexpr (r & 2) p1 |= nw;
            if constexpr (r & 4) p2 |= nw;
            if constexpr (r & 8) p3 |= nw;
        });

        unsigned long long lo = 0, hi = 0;
        static_for<8>([&](auto J) {
            constexpr int j = J.value;
            const unsigned long long f = fw8[w * 8 + j];
            const unsigned int c0 = (unsigned int)((p0 >> (8 * j)) & 0xff);
            const unsigned int c1 = (unsigned int)((p1 >> (8 * j)) & 0xff);
            const unsigned int c2 = (unsigned int)((p2 >> (8 * j)) & 0xff);
            const unsigned int c3 = (unsigned int)((p3 >> (8 * j)) & 0xff);
            const unsigned long long cls = spread8(c0) | (spread8(c1) << 1)
                                         | (spread8(c2) << 2) | (spread8(c3) << 3);
            const unsigned long long cq = (f << 4) | cls;  // fv<=5, no overflow
            sc8[threadIdx.x * 8 + j] = cq;
            static_for<8>([&](auto B) {
                constexpr int b = B.value;
                const unsigned int code = (unsigned int)((cq >> (8 * b)) & 0xff);
                const unsigned long long bit = 1ull << (code & 63);
                const bool ishi = (code & 64) != 0;
                lo |= ishi ? 0ull : bit;
                hi |= ishi ? bit : 0ull;
            });
        });

#pragma unroll
        for (int s = 32; s > 0; s >>= 1) {
            lo |= __shfl_xor(lo, s);
            hi |= __shfl_xor(hi, s);
        }
        if (threadIdx.x == 0) {
            atomicOr(&obs[0], lo);   // device-scope, ordered by barrier release
            atomicOr(&obs[1], hi);
        }
    }

    grid_barrier(cnt);

    // ---- Phase 3: per-block 96-entry table + LDS-code lookup, coalesced out ----
    const int tid = threadIdx.x;
    if (tid < 2)
        sobs[tid] = __hip_atomic_load(&obs[tid], __ATOMIC_RELAXED,
                                      __HIP_MEMORY_SCOPE_AGENT);
    __syncthreads();
    const unsigned long long lo = sobs[0], hi = sobs[1];

    float v = 0.f;
    bool present = false;
    if (tid < 96) {
        const int r = tid & 15;
        const float contour = (r >= 1 && r <= 14) ? 1.f / sqrtf((float)D2S[r]) : 0.f;
        const float t0 = (float)(tid >> 4) + contour;
        v = t0 * t0;
        present = (tid < 64) ? ((lo >> tid) & 1) : ((hi >> (tid - 64)) & 1);
    }
    float mnv = present ? v : INFINITY;
    float mxv = present ? v : -INFINITY;
#pragma unroll
    for (int s = 32; s > 0; s >>= 1) {
        mnv = fminf(mnv, __shfl_xor(mnv, s));
        mxv = fmaxf(mxv, __shfl_xor(mxv, s));
    }
    if ((tid & 63) == 0) { smn[tid >> 6] = mnv; smx[tid >> 6] = mxv; }
    __syncthreads();
    const float mn = fminf(fminf(smn[0], smn[1]), fminf(smn[2], smn[3]));
    const float mx = fmaxf(fmaxf(smx[0], smx[1]), fmaxf(smx[2], smx[3]));
    const float inv = 1.f / (mx - mn + 1e-10f);
    if (tid < 96) tab[tid] = (tid >= 16) ? (v - mn) * inv : 0.f;  // fv==0 -> 0
    __syncthreads();

    const unsigned int* sc32 = (const unsigned int*)sc8;
#pragma unroll
    for (int k = 0; k < 4; ++k) {
        const unsigned int cw = sc32[k * 256 + tid];   // 4 px codes
        float4 o;
        o.x = tab[cw & 0xff];
        o.y = tab[(cw >> 8) & 0xff];
        o.z = tab[(cw >> 16) & 0xff];
        o.w = tab[(cw >> 24) & 0xff];
        *(float4*)(out + blockIdx.x * 4096 + k * 1024 + tid * 4) = o;
    }
}

extern "C" void kernel_launch(void* const* d_in, const int* in_sizes, int n_in,
                              void* d_out, int out_size, void* d_ws, size_t ws_size,
                              hipStream_t stream) {
    const float* target = (const float*)d_in[0];
    float* out = (float*)d_out;

    // ws layout: fw (NPIX B) | pk (NPIX/8 B) | {cnt u32, pad u32, obs u64[2]}
    unsigned long long* fw8 = (unsigned long long*)d_ws;
    unsigned char* pkb = (unsigned char*)d_ws + NPIX;
    unsigned char* barp = pkb + NPIX / 8;
    unsigned* cnt = (unsigned*)barp;
    unsigned long long* obs = (unsigned long long*)(barp + 8);

    // Reset barrier ticket + observed-code mask (graph-capturable memset).
    hipMemsetAsync(barp, 0, 24, stream);

    k_fused<<<NBLK, 256, 0, stream>>>(target, fw8, pkb, cnt, obs, out);
}

// Round 8
// 77.669 us; speedup vs baseline: 2.9147x; 2.7897x over previous
//
#include <hip/hip_runtime.h>
#include <math.h>
#include <utility>

static constexpr int HH = 2048;
static constexpr int WW = 2048;
static constexpr int NPIX = HH * WW;
static constexpr int WPR32 = WW / 32;      // 64 packed u32 words per row

// Compile-time-forced loop unrolling (keeps acc[] in registers).
template <typename F, int... Is>
__device__ __forceinline__ void sf_impl(F&& f, std::integer_sequence<int, Is...>) {
    (f(std::integral_constant<int, Is>{}), ...);
}
template <int N, typename F>
__device__ __forceinline__ void static_for(F&& f) {
    sf_impl(f, std::make_integer_sequence<int, N>{});
}

// Rank of squared distance among the 14 distinct d2 values in the 9x9
// neighborhood (ascending). 0 = "no differing neighbor".
__host__ __device__ constexpr int rank_of(int d2) {
    switch (d2) {
        case 1:  return 1;  case 2:  return 2;  case 4:  return 3;
        case 5:  return 4;  case 8:  return 5;  case 9:  return 6;
        case 10: return 7;  case 13: return 8;  case 16: return 9;
        case 17: return 10; case 18: return 11; case 20: return 12;
        case 25: return 13; case 32: return 14;
    }
    return 0;
}

__device__ const int D2S[16] = {0, 1, 2, 4, 5, 8, 9, 10, 13, 16, 17, 18, 20, 25, 32, 0};

// Spread the 8 bits of b into the 8 bytes of a u64 (byte i = (b>>i)&1).
__device__ __forceinline__ unsigned long long spread8(unsigned int b) {
    unsigned long long t = (unsigned long long)b * 0x0101010101010101ull;
    t &= 0x8040201008040201ull;
    return ((t + 0x7f7f7f7f7f7f7f7full) >> 7) & 0x0101010101010101ull;
}

// Pass A: fw byte map (sum of 5 binary masks) + bit-packed combined mask.
// Also zeroes the observed-code mask (read only by the NEXT kernel).
__global__ __launch_bounds__(256) void k_pack(const float* __restrict__ t,
                                              unsigned char* __restrict__ fw,
                                              unsigned char* __restrict__ pk,
                                              unsigned long long* __restrict__ obs) {
    const int tid = blockIdx.x * 256 + threadIdx.x;
    if (tid == 0) { obs[0] = 0ull; obs[1] = 0ull; }
    const int base = tid * 8;
    unsigned long long fwq = 0;
    unsigned int bits = 0;
#pragma unroll
    for (int h = 0; h < 2; ++h) {
        const int o = base + 4 * h;
        float4 a = *(const float4*)(t + 0 * NPIX + o);
        float4 b = *(const float4*)(t + 1 * NPIX + o);
        float4 c = *(const float4*)(t + 2 * NPIX + o);
        float4 d = *(const float4*)(t + 3 * NPIX + o);
        float4 e = *(const float4*)(t + 4 * NPIX + o);
        const float s0 = a.x + b.x + c.x + d.x + e.x;
        const float s1 = a.y + b.y + c.y + d.y + e.y;
        const float s2 = a.z + b.z + c.z + d.z + e.z;
        const float s3 = a.w + b.w + c.w + d.w + e.w;
        const int j = 4 * h;
        fwq |= ((unsigned long long)(int)s0) << (8 * j);
        fwq |= ((unsigned long long)(int)s1) << (8 * (j + 1));
        fwq |= ((unsigned long long)(int)s2) << (8 * (j + 2));
        fwq |= ((unsigned long long)(int)s3) << (8 * (j + 3));
        bits |= (s0 > 0.f ? 1u : 0u) << j;
        bits |= (s1 > 0.f ? 1u : 0u) << (j + 1);
        bits |= (s2 > 0.f ? 1u : 0u) << (j + 2);
        bits |= (s3 > 0.f ? 1u : 0u) << (j + 3);
    }
    *(unsigned long long*)(fw + base) = fwq;
    pk[tid] = (unsigned char)bits;
}

// Pass B: bit-parallel min-squared-distance classification.
// u32 word granularity (131072 threads = 2 waves/SIMD for latency hiding).
// Block = 8 full image rows; pk tile (8 + 8 halo rows) staged in LDS so the
// 27 neighborhood reads are ds_read_b32 instead of exposed L1/L2 latency.
__global__ __launch_bounds__(512) void k_dist(const unsigned* __restrict__ pk32,
                                              const unsigned long long* __restrict__ fw8,
                                              unsigned long long* __restrict__ code8,
                                              unsigned long long* __restrict__ obs) {
    __shared__ unsigned tile[16][WPR32];   // 16 rows x 64 u32 = 4 KB

    const int y0 = blockIdx.x * 8;
    // Cooperative halo load: rows clamp(y0-4 .. y0+11), full width.
#pragma unroll
    for (int k = 0; k < 2; ++k) {
        const int idx = threadIdx.x + k * 512;
        const int r = idx >> 6;
        const int wx = idx & 63;
        const int gy = min(max(y0 - 4 + r, 0), HH - 1);
        tile[r][wx] = pk32[gy * WPR32 + wx];
    }
    __syncthreads();

    const int ty = threadIdx.x >> 6;           // 0..7 (row within block)
    const int wx = threadIdx.x & 63;           // u32 word within row
    const int t = (y0 + ty) * WPR32 + wx;      // global u32-word index

    unsigned acc[15];
    static_for<15>([&](auto I) { acc[I.value] = 0u; });

    const unsigned C = tile[ty + 4][wx];

    static_for<9>([&](auto DY) {
        constexpr int dy = DY.value - 4;
        const int r = ty + dy + 4;
        const unsigned M = tile[r][wx];
        const unsigned L = (wx > 0) ? tile[r][wx - 1] : ((M & 1u) ? ~0u : 0u);
        const unsigned R = (wx < WPR32 - 1) ? tile[r][wx + 1]
                                            : ((M >> 31) ? ~0u : 0u);
        static_for<9>([&](auto DX) {
            constexpr int dx = DX.value - 4;
            if constexpr (!(dx == 0 && dy == 0)) {
                constexpr int rk = rank_of(dy * dy + dx * dx);
                unsigned S;
                if constexpr (dx > 0)      S = (M >> dx) | (R << (32 - dx));
                else if constexpr (dx < 0) S = (M << (-dx)) | (L >> (32 + dx));
                else                       S = M;
                acc[rk] |= S ^ C;
            }
        });
    });

    // Resolve ascending distance into 4 bitplanes (first-found = min d2).
    unsigned found = 0, p0 = 0, p1 = 0, p2 = 0, p3 = 0;
    static_for<14>([&](auto RI) {
        constexpr int r = RI.value + 1;
        const unsigned nw = acc[r] & ~found;
        found |= acc[r];
        if constexpr (r & 1) p0 |= nw;
        if constexpr (r & 2) p1 |= nw;
        if constexpr (r & 4) p2 |= nw;
        if constexpr (r & 8) p3 |= nw;
    });

    // Epilogue: emit code bytes (code = fv<<4 | class); track observed codes.
    unsigned long long lo = 0, hi = 0;
    static_for<4>([&](auto J) {
        constexpr int j = J.value;
        const unsigned long long f = fw8[t * 4 + j];
        const unsigned int c0 = (p0 >> (8 * j)) & 0xff;
        const unsigned int c1 = (p1 >> (8 * j)) & 0xff;
        const unsigned int c2 = (p2 >> (8 * j)) & 0xff;
        const unsigned int c3 = (p3 >> (8 * j)) & 0xff;
        const unsigned long long cls = spread8(c0) | (spread8(c1) << 1)
                                     | (spread8(c2) << 2) | (spread8(c3) << 3);
        const unsigned long long cq = (f << 4) | cls;   // fv<=5, no overflow
        code8[t * 4 + j] = cq;
        static_for<8>([&](auto B) {
            constexpr int b = B.value;
            const unsigned int code = (unsigned int)((cq >> (8 * b)) & 0xff);
            const unsigned long long bit = 1ull << (code & 63);
            const bool ishi = (code & 64) != 0;
            lo |= ishi ? 0ull : bit;
            hi |= ishi ? bit : 0ull;
        });
    });

    // Wave OR-reduce, one atomicOr pair per wave (idempotent -> deterministic).
#pragma unroll
    for (int s = 32; s > 0; s >>= 1) {
        lo |= __shfl_xor(lo, s);
        hi |= __shfl_xor(hi, s);
    }
    if ((threadIdx.x & 63) == 0) {
        atomicOr(&obs[0], lo);
        atomicOr(&obs[1], hi);
    }
}

// Pass C: per-block table build (96 parallel lanes) + LDS-table lookup.
__global__ __launch_bounds__(256) void k_out(const unsigned long long* __restrict__ code8,
                                             const unsigned long long* __restrict__ obs,
                                             float* __restrict__ out) {
    __shared__ float tab[96];
    __shared__ float smn[4], smx[4];

    const int tid = threadIdx.x;
    const unsigned long long lo = obs[0], hi = obs[1];

    float v = 0.f;
    bool present = false;
    if (tid < 96) {
        const int r = tid & 15;
        const float contour = (r >= 1 && r <= 14) ? 1.f / sqrtf((float)D2S[r]) : 0.f;
        const float t0 = (float)(tid >> 4) + contour;
        v = t0 * t0;
        present = (tid < 64) ? ((lo >> tid) & 1) : ((hi >> (tid - 64)) & 1);
    }
    float mnv = present ? v : INFINITY;
    float mxv = present ? v : -INFINITY;
#pragma unroll
    for (int s = 32; s > 0; s >>= 1) {
        mnv = fminf(mnv, __shfl_xor(mnv, s));
        mxv = fmaxf(mxv, __shfl_xor(mxv, s));
    }
    if ((tid & 63) == 0) { smn[tid >> 6] = mnv; smx[tid >> 6] = mxv; }
    __syncthreads();
    const float mn = fminf(fminf(smn[0], smn[1]), fminf(smn[2], smn[3]));
    const float mx = fmaxf(fmaxf(smx[0], smx[1]), fmaxf(smx[2], smx[3]));
    const float inv = 1.f / (mx - mn + 1e-10f);
    if (tid < 96) tab[tid] = (tid >= 16) ? (v - mn) * inv : 0.f;  // fv==0 -> 0
    __syncthreads();

    const int t = blockIdx.x * 256 + tid;
    const unsigned long long cq = code8[t];
    float4 v0, v1;
    v0.x = tab[(cq >> 0) & 0xff];
    v0.y = tab[(cq >> 8) & 0xff];
    v0.z = tab[(cq >> 16) & 0xff];
    v0.w = tab[(cq >> 24) & 0xff];
    v1.x = tab[(cq >> 32) & 0xff];
    v1.y = tab[(cq >> 40) & 0xff];
    v1.z = tab[(cq >> 48) & 0xff];
    v1.w = tab[(cq >> 56) & 0xff];
    *(float4*)(out + t * 8) = v0;
    *(float4*)(out + t * 8 + 4) = v1;
}

extern "C" void kernel_launch(void* const* d_in, const int* in_sizes, int n_in,
                              void* d_out, int out_size, void* d_ws, size_t ws_size,
                              hipStream_t stream) {
    const float* target = (const float*)d_in[0];
    float* out = (float*)d_out;

    // ws layout (8B-aligned): fw | packed | code | obs
    unsigned char* fw = (unsigned char*)d_ws;                         // NPIX bytes
    unsigned char* pk = fw + NPIX;                                    // NPIX/8 bytes
    unsigned char* code = pk + NPIX / 8;                              // NPIX bytes
    unsigned long long* obs = (unsigned long long*)(code + NPIX);     // 16 bytes

    k_pack<<<NPIX / 8 / 256, 256, 0, stream>>>(target, fw, pk, obs);

    k_dist<<<HH / 8, 512, 0, stream>>>(
        (const unsigned*)pk, (const unsigned long long*)fw,
        (unsigned long long*)code, obs);

    k_out<<<NPIX / 8 / 256, 256, 0, stream>>>(
        (const unsigned long long*)code, obs, out);
}

// Round 9
// 38.082 us; speedup vs baseline: 5.9446x; 2.0395x over previous
//
#include <hip/hip_runtime.h>
#include <math.h>
#include <utility>

static constexpr int HH = 2048;
static constexpr int WW = 2048;
static constexpr int NPIX = HH * WW;
static constexpr int WPR32 = WW / 32;      // 64 packed u32 words per row
static constexpr int NWAVE_DIST = 2048;    // 256 blocks x 8 waves

// Compile-time-forced loop unrolling (keeps acc[] in registers).
template <typename F, int... Is>
__device__ __forceinline__ void sf_impl(F&& f, std::integer_sequence<int, Is...>) {
    (f(std::integral_constant<int, Is>{}), ...);
}
template <int N, typename F>
__device__ __forceinline__ void static_for(F&& f) {
    sf_impl(f, std::make_integer_sequence<int, N>{});
}

// Rank of squared distance among the 14 distinct d2 values in the 9x9
// neighborhood (ascending). 0 = "no differing neighbor".
__host__ __device__ constexpr int rank_of(int d2) {
    switch (d2) {
        case 1:  return 1;  case 2:  return 2;  case 4:  return 3;
        case 5:  return 4;  case 8:  return 5;  case 9:  return 6;
        case 10: return 7;  case 13: return 8;  case 16: return 9;
        case 17: return 10; case 18: return 11; case 20: return 12;
        case 25: return 13; case 32: return 14;
    }
    return 0;
}

__device__ const int D2S[16] = {0, 1, 2, 4, 5, 8, 9, 10, 13, 16, 17, 18, 20, 25, 32, 0};

// Spread the 8 bits of b into the 8 bytes of a u64 (byte i = (b>>i)&1).
__device__ __forceinline__ unsigned long long spread8(unsigned int b) {
    unsigned long long t = (unsigned long long)b * 0x0101010101010101ull;
    t &= 0x8040201008040201ull;
    return ((t + 0x7f7f7f7f7f7f7f7full) >> 7) & 0x0101010101010101ull;
}

// Pass A: fw byte map (sum of 5 binary masks) + bit-packed combined mask.
__global__ __launch_bounds__(256) void k_pack(const float* __restrict__ t,
                                              unsigned char* __restrict__ fw,
                                              unsigned char* __restrict__ pk) {
    const int tid = blockIdx.x * 256 + threadIdx.x;
    const int base = tid * 8;
    unsigned long long fwq = 0;
    unsigned int bits = 0;
#pragma unroll
    for (int h = 0; h < 2; ++h) {
        const int o = base + 4 * h;
        float4 a = *(const float4*)(t + 0 * NPIX + o);
        float4 b = *(const float4*)(t + 1 * NPIX + o);
        float4 c = *(const float4*)(t + 2 * NPIX + o);
        float4 d = *(const float4*)(t + 3 * NPIX + o);
        float4 e = *(const float4*)(t + 4 * NPIX + o);
        const float s0 = a.x + b.x + c.x + d.x + e.x;
        const float s1 = a.y + b.y + c.y + d.y + e.y;
        const float s2 = a.z + b.z + c.z + d.z + e.z;
        const float s3 = a.w + b.w + c.w + d.w + e.w;
        const int j = 4 * h;
        fwq |= ((unsigned long long)(int)s0) << (8 * j);
        fwq |= ((unsigned long long)(int)s1) << (8 * (j + 1));
        fwq |= ((unsigned long long)(int)s2) << (8 * (j + 2));
        fwq |= ((unsigned long long)(int)s3) << (8 * (j + 3));
        bits |= (s0 > 0.f ? 1u : 0u) << j;
        bits |= (s1 > 0.f ? 1u : 0u) << (j + 1);
        bits |= (s2 > 0.f ? 1u : 0u) << (j + 2);
        bits |= (s3 > 0.f ? 1u : 0u) << (j + 3);
    }
    *(unsigned long long*)(fw + base) = fwq;
    pk[tid] = (unsigned char)bits;
}

// Pass B: bit-parallel min-squared-distance classification.
// IDENTICAL to R8 except: NO global atomics — each wave stores its observed-
// code mask (lo,hi) to a private slot (R8 evidence: 4096 same-line device
// atomicOrs <=> ~52us at ~30cy serialized each; disjoint stores are free).
__global__ __launch_bounds__(512) void k_dist(const unsigned* __restrict__ pk32,
                                              const unsigned long long* __restrict__ fw8,
                                              unsigned long long* __restrict__ code8,
                                              unsigned long long* __restrict__ obs_slots) {
    __shared__ unsigned tile[16][WPR32];   // 16 rows x 64 u32 = 4 KB

    const int y0 = blockIdx.x * 8;
    // Cooperative halo load: rows clamp(y0-4 .. y0+11), full width.
#pragma unroll
    for (int k = 0; k < 2; ++k) {
        const int idx = threadIdx.x + k * 512;
        const int r = idx >> 6;
        const int wx = idx & 63;
        const int gy = min(max(y0 - 4 + r, 0), HH - 1);
        tile[r][wx] = pk32[gy * WPR32 + wx];
    }
    __syncthreads();

    const int ty = threadIdx.x >> 6;           // 0..7 (row within block)
    const int wx = threadIdx.x & 63;           // u32 word within row
    const int t = (y0 + ty) * WPR32 + wx;      // global u32-word index

    unsigned acc[15];
    static_for<15>([&](auto I) { acc[I.value] = 0u; });

    const unsigned C = tile[ty + 4][wx];

    static_for<9>([&](auto DY) {
        constexpr int dy = DY.value - 4;
        const int r = ty + dy + 4;
        const unsigned M = tile[r][wx];
        const unsigned L = (wx > 0) ? tile[r][wx - 1] : ((M & 1u) ? ~0u : 0u);
        const unsigned R = (wx < WPR32 - 1) ? tile[r][wx + 1]
                                            : ((M >> 31) ? ~0u : 0u);
        static_for<9>([&](auto DX) {
            constexpr int dx = DX.value - 4;
            if constexpr (!(dx == 0 && dy == 0)) {
                constexpr int rk = rank_of(dy * dy + dx * dx);
                unsigned S;
                if constexpr (dx > 0)      S = (M >> dx) | (R << (32 - dx));
                else if constexpr (dx < 0) S = (M << (-dx)) | (L >> (32 + dx));
                else                       S = M;
                acc[rk] |= S ^ C;
            }
        });
    });

    // Resolve ascending distance into 4 bitplanes (first-found = min d2).
    unsigned found = 0, p0 = 0, p1 = 0, p2 = 0, p3 = 0;
    static_for<14>([&](auto RI) {
        constexpr int r = RI.value + 1;
        const unsigned nw = acc[r] & ~found;
        found |= acc[r];
        if constexpr (r & 1) p0 |= nw;
        if constexpr (r & 2) p1 |= nw;
        if constexpr (r & 4) p2 |= nw;
        if constexpr (r & 8) p3 |= nw;
    });

    // Epilogue: emit code bytes (code = fv<<4 | class); track observed codes.
    unsigned long long lo = 0, hi = 0;
    static_for<4>([&](auto J) {
        constexpr int j = J.value;
        const unsigned long long f = fw8[t * 4 + j];
        const unsigned int c0 = (p0 >> (8 * j)) & 0xff;
        const unsigned int c1 = (p1 >> (8 * j)) & 0xff;
        const unsigned int c2 = (p2 >> (8 * j)) & 0xff;
        const unsigned int c3 = (p3 >> (8 * j)) & 0xff;
        const unsigned long long cls = spread8(c0) | (spread8(c1) << 1)
                                     | (spread8(c2) << 2) | (spread8(c3) << 3);
        const unsigned long long cq = (f << 4) | cls;   // fv<=5, no overflow
        code8[t * 4 + j] = cq;
        static_for<8>([&](auto B) {
            constexpr int b = B.value;
            const unsigned int code = (unsigned int)((cq >> (8 * b)) & 0xff);
            const unsigned long long bit = 1ull << (code & 63);
            const bool ishi = (code & 64) != 0;
            lo |= ishi ? 0ull : bit;
            hi |= ishi ? bit : 0ull;
        });
    });

    // Wave OR-reduce, then ONE plain store pair per wave (disjoint slots).
#pragma unroll
    for (int s = 32; s > 0; s >>= 1) {
        lo |= __shfl_xor(lo, s);
        hi |= __shfl_xor(hi, s);
    }
    if ((threadIdx.x & 63) == 0) {
        const int wave = blockIdx.x * 8 + (threadIdx.x >> 6);
        obs_slots[wave * 2]     = lo;
        obs_slots[wave * 2 + 1] = hi;
    }
}

// Pass C: OR-reduce the 2048 per-wave obs slots (32 KB, L2-broadcast), build
// the 96-entry table, then LDS-table lookup.
__global__ __launch_bounds__(256) void k_out(const unsigned long long* __restrict__ code8,
                                             const unsigned long long* __restrict__ obs_slots,
                                             float* __restrict__ out) {
    __shared__ float tab[96];
    __shared__ float smn[4], smx[4];
    __shared__ unsigned long long slo[4], shi[4];

    const int tid = threadIdx.x;

    // Preamble: global obs = OR of all per-wave slots.
    unsigned long long lo = 0, hi = 0;
    {
        const ulonglong2* sl2 = (const ulonglong2*)obs_slots;
#pragma unroll
        for (int i = 0; i < 8; ++i) {
            const ulonglong2 s = sl2[tid * 8 + i];   // 256 thr x 8 = 2048 slots
            lo |= s.x;
            hi |= s.y;
        }
#pragma unroll
        for (int s = 32; s > 0; s >>= 1) {
            lo |= __shfl_xor(lo, s);
            hi |= __shfl_xor(hi, s);
        }
        if ((tid & 63) == 0) { slo[tid >> 6] = lo; shi[tid >> 6] = hi; }
        __syncthreads();
        lo = slo[0] | slo[1] | slo[2] | slo[3];
        hi = shi[0] | shi[1] | shi[2] | shi[3];
    }

    float v = 0.f;
    bool present = false;
    if (tid < 96) {
        const int r = tid & 15;
        const float contour = (r >= 1 && r <= 14) ? 1.f / sqrtf((float)D2S[r]) : 0.f;
        const float t0 = (float)(tid >> 4) + contour;
        v = t0 * t0;
        present = (tid < 64) ? ((lo >> tid) & 1) : ((hi >> (tid - 64)) & 1);
    }
    float mnv = present ? v : INFINITY;
    float mxv = present ? v : -INFINITY;
#pragma unroll
    for (int s = 32; s > 0; s >>= 1) {
        mnv = fminf(mnv, __shfl_xor(mnv, s));
        mxv = fmaxf(mxv, __shfl_xor(mxv, s));
    }
    if ((tid & 63) == 0) { smn[tid >> 6] = mnv; smx[tid >> 6] = mxv; }
    __syncthreads();
    const float mn = fminf(fminf(smn[0], smn[1]), fminf(smn[2], smn[3]));
    const float mx = fmaxf(fmaxf(smx[0], smx[1]), fmaxf(smx[2], smx[3]));
    const float inv = 1.f / (mx - mn + 1e-10f);
    if (tid < 96) tab[tid] = (tid >= 16) ? (v - mn) * inv : 0.f;  // fv==0 -> 0
    __syncthreads();

    const int t = blockIdx.x * 256 + tid;
    const unsigned long long cq = code8[t];
    float4 v0, v1;
    v0.x = tab[(cq >> 0) & 0xff];
    v0.y = tab[(cq >> 8) & 0xff];
    v0.z = tab[(cq >> 16) & 0xff];
    v0.w = tab[(cq >> 24) & 0xff];
    v1.x = tab[(cq >> 32) & 0xff];
    v1.y = tab[(cq >> 40) & 0xff];
    v1.z = tab[(cq >> 48) & 0xff];
    v1.w = tab[(cq >> 56) & 0xff];
    *(float4*)(out + t * 8) = v0;
    *(float4*)(out + t * 8 + 4) = v1;
}

extern "C" void kernel_launch(void* const* d_in, const int* in_sizes, int n_in,
                              void* d_out, int out_size, void* d_ws, size_t ws_size,
                              hipStream_t stream) {
    const float* target = (const float*)d_in[0];
    float* out = (float*)d_out;

    // ws layout (16B-aligned sections): fw | packed | code | obs_slots
    unsigned char* fw = (unsigned char*)d_ws;                         // NPIX bytes
    unsigned char* pk = fw + NPIX;                                    // NPIX/8 bytes
    unsigned char* code = pk + NPIX / 8;                              // NPIX bytes
    unsigned long long* obs_slots = (unsigned long long*)(code + NPIX); // 2048*16 B

    k_pack<<<NPIX / 8 / 256, 256, 0, stream>>>(target, fw, pk);

    k_dist<<<HH / 8, 512, 0, stream>>>(
        (const unsigned*)pk, (const unsigned long long*)fw,
        (unsigned long long*)code, obs_slots);

    k_out<<<NPIX / 8 / 256, 256, 0, stream>>>(
        (const unsigned long long*)code, obs_slots, out);
}